// Round 2
// baseline (558.647 us; speedup 1.0000x reference)
//
#include <hip/hip_runtime.h>
#include <hip/hip_bf16.h>

#define D 96
#define DQ 24   // D/4 float4 groups per row

// ---------------------------------------------------------------------------
// 1) histogram of dst -> cnt[n]
__global__ __launch_bounds__(256) void hist_kernel(const int* __restrict__ dst,
                                                   int* __restrict__ cnt, int E) {
    int e = blockIdx.x * 256 + threadIdx.x;
    if (e < E) atomicAdd(&cnt[dst[e]], 1);
}

// ---------------------------------------------------------------------------
// 2) exclusive scan cnt[0..n) -> rs[0..n], rs[n]=total. Single block of 1024.
__global__ __launch_bounds__(1024) void scan_kernel(const int* __restrict__ cnt,
                                                    int* __restrict__ rs, int n) {
    __shared__ int part[1024];
    int t = threadIdx.x;
    int chunk = (n + 1023) / 1024;
    int beg = t * chunk;
    int end = beg + chunk; if (end > n) end = n;
    int s = 0;
    for (int i = beg; i < end; ++i) s += cnt[i];
    part[t] = s;
    __syncthreads();
    // Hillis-Steele inclusive scan over 1024 entries
    for (int off = 1; off < 1024; off <<= 1) {
        int v = (t >= off) ? part[t - off] : 0;
        __syncthreads();
        part[t] += v;
        __syncthreads();
    }
    int running = part[t] - s;  // exclusive prefix for this thread's chunk
    for (int i = beg; i < end; ++i) {
        rs[i] = running;
        running += cnt[i];
    }
    if (end == n && beg < n) rs[n] = running;  // total == E
}

// ---------------------------------------------------------------------------
// 3) fill CSR column (source node) list
__global__ __launch_bounds__(256) void fill_kernel(const int* __restrict__ src,
                                                   const int* __restrict__ dst,
                                                   const int* __restrict__ rs,
                                                   int* __restrict__ cur,
                                                   int* __restrict__ col, int E) {
    int e = blockIdx.x * 256 + threadIdx.x;
    if (e < E) {
        int d = dst[e];
        int pos = rs[d] + atomicAdd(&cur[d], 1);
        col[pos] = src[e];
    }
}

// ---------------------------------------------------------------------------
// 4) mean aggregation: agg[n][:] = mean over incoming edges of h[src][:]
//    one thread per (node, float4-group): idx = n*24 + q.
//    2-deep unroll: two independent gather chains in flight per lane.
__global__ __launch_bounds__(256) void aggregate_kernel(const float* __restrict__ h,
                                                        const int* __restrict__ rs,
                                                        const int* __restrict__ col,
                                                        float* __restrict__ agg, int n) {
    int idx = blockIdx.x * 256 + threadIdx.x;
    if (idx >= n * DQ) return;
    int node = idx / DQ;
    int q = idx - node * DQ;
    int beg = rs[node], end = rs[node + 1];
    float ax0 = 0.f, ay0 = 0.f, az0 = 0.f, aw0 = 0.f;
    float ax1 = 0.f, ay1 = 0.f, az1 = 0.f, aw1 = 0.f;
    int i = beg;
    for (; i + 2 <= end; i += 2) {
        int s0 = col[i], s1 = col[i + 1];
        const float4 v0 = *(const float4*)(h + (size_t)s0 * D + q * 4);
        const float4 v1 = *(const float4*)(h + (size_t)s1 * D + q * 4);
        ax0 += v0.x; ay0 += v0.y; az0 += v0.z; aw0 += v0.w;
        ax1 += v1.x; ay1 += v1.y; az1 += v1.z; aw1 += v1.w;
    }
    if (i < end) {
        int s0 = col[i];
        const float4 v0 = *(const float4*)(h + (size_t)s0 * D + q * 4);
        ax0 += v0.x; ay0 += v0.y; az0 += v0.z; aw0 += v0.w;
    }
    float inv = 1.0f / fmaxf((float)(end - beg), 1.0f);
    float4 o;
    o.x = (ax0 + ax1) * inv; o.y = (ay0 + ay1) * inv;
    o.z = (az0 + az1) * inv; o.w = (aw0 + aw1) * inv;
    *(float4*)(agg + (size_t)node * D + q * 4) = o;
}

// ---------------------------------------------------------------------------
// 5) fused SAGE linear: out[n][o] = agg[n]·Wl[o] + bl[o] + hin[n]·Wr[o] (+relu)
//    block (48,4) = 192 threads; 16 rows/block; thread: 4 rows x 2 cols.
__global__ __launch_bounds__(192) void sage_gemm_kernel(const float* __restrict__ agg,
                                                        const float* __restrict__ hin,
                                                        const float* __restrict__ Wl,
                                                        const float* __restrict__ bl,
                                                        const float* __restrict__ Wr,
                                                        float* __restrict__ out,
                                                        int relu) {
    __shared__ float vA[16][D];
    __shared__ float vX[16][D];
    int tid = threadIdx.y * 48 + threadIdx.x;
    int row0 = blockIdx.x * 16;

    // stage 16 rows of agg and hin (384 float4 each)
    const float4* av = (const float4*)(agg + (size_t)row0 * D);
    const float4* hv = (const float4*)(hin + (size_t)row0 * D);
    for (int i = tid; i < 384; i += 192) ((float4*)vA)[i] = av[i];
    for (int i = tid; i < 384; i += 192) ((float4*)vX)[i] = hv[i];
    __syncthreads();

    int o0 = threadIdx.x;       // cols o0 and o0+48
    const float4* wl0 = (const float4*)(Wl + (size_t)o0 * D);
    const float4* wl1 = (const float4*)(Wl + (size_t)(o0 + 48) * D);
    const float4* wr0 = (const float4*)(Wr + (size_t)o0 * D);
    const float4* wr1 = (const float4*)(Wr + (size_t)(o0 + 48) * D);

    float acc[4][2];
    #pragma unroll
    for (int j = 0; j < 4; ++j) { acc[j][0] = 0.f; acc[j][1] = 0.f; }

    #pragma unroll 4
    for (int k4 = 0; k4 < DQ; ++k4) {
        float4 l0 = wl0[k4], l1 = wl1[k4];
        float4 r0 = wr0[k4], r1 = wr1[k4];
        #pragma unroll
        for (int j = 0; j < 4; ++j) {
            int r = threadIdx.y + 4 * j;
            float4 va = *(const float4*)&vA[r][k4 * 4];
            float4 vx = *(const float4*)&vX[r][k4 * 4];
            acc[j][0] += va.x * l0.x + va.y * l0.y + va.z * l0.z + va.w * l0.w
                       + vx.x * r0.x + vx.y * r0.y + vx.z * r0.z + vx.w * r0.w;
            acc[j][1] += va.x * l1.x + va.y * l1.y + va.z * l1.z + va.w * l1.w
                       + vx.x * r1.x + vx.y * r1.y + vx.z * r1.z + vx.w * r1.w;
        }
    }

    float b0 = bl[o0], b1 = bl[o0 + 48];
    #pragma unroll
    for (int j = 0; j < 4; ++j) {
        int r = threadIdx.y + 4 * j;
        float v0 = acc[j][0] + b0;
        float v1 = acc[j][1] + b1;
        if (relu) { v0 = fmaxf(v0, 0.f); v1 = fmaxf(v1, 0.f); }
        out[(size_t)(row0 + r) * D + o0] = v0;
        out[(size_t)(row0 + r) * D + o0 + 48] = v1;
    }
}

// ---------------------------------------------------------------------------
extern "C" void kernel_launch(void* const* d_in, const int* in_sizes, int n_in,
                              void* d_out, int out_size, void* d_ws, size_t ws_size,
                              hipStream_t stream) {
    const float* x   = (const float*)d_in[0];
    const int*   ei  = (const int*)d_in[1];
    const float* Wl1 = (const float*)d_in[2];
    const float* bl1 = (const float*)d_in[3];
    const float* Wr1 = (const float*)d_in[4];
    const float* Wl2 = (const float*)d_in[5];
    const float* bl2 = (const float*)d_in[6];
    const float* Wr2 = (const float*)d_in[7];
    float* out = (float*)d_out;

    int N = in_sizes[0] / D;      // 50000
    int E = in_sizes[1] / 2;      // 800000
    const int* src = ei;
    const int* dst = ei + E;

    // workspace layout (~42.2 MB)
    char* ws = (char*)d_ws;
    float* agg = (float*)ws;                         // N*D floats
    float* h1  = agg + (size_t)N * D;                // N*D floats
    int*   rs  = (int*)(h1 + (size_t)N * D);         // N+1
    int*   cnt = rs + (N + 1);                       // N
    int*   cur = cnt + N;                            // N
    int*   col = cur + N;                            // E

    // zero cnt and cur in one shot (adjacent)
    hipMemsetAsync(cnt, 0, (size_t)2 * N * sizeof(int), stream);

    int eb = (E + 255) / 256;
    hist_kernel<<<eb, 256, 0, stream>>>(dst, cnt, E);
    scan_kernel<<<1, 1024, 0, stream>>>(cnt, rs, N);
    fill_kernel<<<eb, 256, 0, stream>>>(src, dst, rs, cur, col, E);

    int ab = (N * DQ + 255) / 256;
    dim3 gblock(48, 4);
    int ggrid = (N + 15) / 16;

    // layer 1
    aggregate_kernel<<<ab, 256, 0, stream>>>(x, rs, col, agg, N);
    sage_gemm_kernel<<<ggrid, gblock, 0, stream>>>(agg, x, Wl1, bl1, Wr1, h1, 1);

    // layer 2
    aggregate_kernel<<<ab, 256, 0, stream>>>(h1, rs, col, agg, N);
    sage_gemm_kernel<<<ggrid, gblock, 0, stream>>>(agg, h1, Wl2, bl2, Wr2, out, 0);
}

// Round 9
// 443.715 us; speedup vs baseline: 1.2590x; 1.2590x over previous
//
#include <hip/hip_runtime.h>
#include <hip/hip_bf16.h>

#define D 96
#define DQ 24    // D/4 float4 groups per row
#define PAD 100  // padded LDS row stride (floats): weight reads 2-way (free), A reads conflict-free

// ---------------------------------------------------------------------------
// 1) histogram of dst -> cnt[n]
__global__ __launch_bounds__(256) void hist_kernel(const int* __restrict__ dst,
                                                   int* __restrict__ cnt, int E) {
    int e = blockIdx.x * 256 + threadIdx.x;
    if (e < E) atomicAdd(&cnt[dst[e]], 1);
}

// ---------------------------------------------------------------------------
// 2) exclusive scan cnt[0..n) -> rs[0..n], rs[n]=total. Single block of 1024.
__global__ __launch_bounds__(1024) void scan_kernel(const int* __restrict__ cnt,
                                                    int* __restrict__ rs, int n) {
    __shared__ int part[1024];
    int t = threadIdx.x;
    int chunk = (n + 1023) / 1024;
    int beg = t * chunk;
    int end = beg + chunk; if (end > n) end = n;
    int s = 0;
    for (int i = beg; i < end; ++i) s += cnt[i];
    part[t] = s;
    __syncthreads();
    for (int off = 1; off < 1024; off <<= 1) {
        int v = (t >= off) ? part[t - off] : 0;
        __syncthreads();
        part[t] += v;
        __syncthreads();
    }
    int running = part[t] - s;
    for (int i = beg; i < end; ++i) {
        rs[i] = running;
        running += cnt[i];
    }
    if (end == n && beg < n) rs[n] = running;
}

// ---------------------------------------------------------------------------
// 3) fill CSR column (source node) list
__global__ __launch_bounds__(256) void fill_kernel(const int* __restrict__ src,
                                                   const int* __restrict__ dst,
                                                   const int* __restrict__ rs,
                                                   int* __restrict__ cur,
                                                   int* __restrict__ col, int E) {
    int e = blockIdx.x * 256 + threadIdx.x;
    if (e < E) {
        int d = dst[e];
        int pos = rs[d] + atomicAdd(&cur[d], 1);
        col[pos] = src[e];
    }
}

// ---------------------------------------------------------------------------
// 4) mean aggregation: thread = (node, float4-group). 4 independent gather
//    chains in flight (latency-bound on col->gather dependent chain).
__global__ __launch_bounds__(256) void aggregate_kernel(const float* __restrict__ h,
                                                        const int* __restrict__ rs,
                                                        const int* __restrict__ col,
                                                        float* __restrict__ agg, int n) {
    int idx = blockIdx.x * 256 + threadIdx.x;
    if (idx >= n * DQ) return;
    int node = idx / DQ;
    int q = idx - node * DQ;
    int beg = rs[node], end = rs[node + 1];
    float ax0=0.f, ay0=0.f, az0=0.f, aw0=0.f;
    float ax1=0.f, ay1=0.f, az1=0.f, aw1=0.f;
    float ax2=0.f, ay2=0.f, az2=0.f, aw2=0.f;
    float ax3=0.f, ay3=0.f, az3=0.f, aw3=0.f;
    int i = beg;
    for (; i + 4 <= end; i += 4) {
        int s0 = col[i], s1 = col[i+1], s2 = col[i+2], s3 = col[i+3];
        const float4 v0 = *(const float4*)(h + (size_t)s0 * D + q * 4);
        const float4 v1 = *(const float4*)(h + (size_t)s1 * D + q * 4);
        const float4 v2 = *(const float4*)(h + (size_t)s2 * D + q * 4);
        const float4 v3 = *(const float4*)(h + (size_t)s3 * D + q * 4);
        ax0 += v0.x; ay0 += v0.y; az0 += v0.z; aw0 += v0.w;
        ax1 += v1.x; ay1 += v1.y; az1 += v1.z; aw1 += v1.w;
        ax2 += v2.x; ay2 += v2.y; az2 += v2.z; aw2 += v2.w;
        ax3 += v3.x; ay3 += v3.y; az3 += v3.z; aw3 += v3.w;
    }
    for (; i < end; ++i) {
        int s0 = col[i];
        const float4 v0 = *(const float4*)(h + (size_t)s0 * D + q * 4);
        ax0 += v0.x; ay0 += v0.y; az0 += v0.z; aw0 += v0.w;
    }
    float inv = 1.0f / fmaxf((float)(end - beg), 1.0f);
    float4 o;
    o.x = (ax0 + ax1 + ax2 + ax3) * inv;
    o.y = (ay0 + ay1 + ay2 + ay3) * inv;
    o.z = (az0 + az1 + az2 + az3) * inv;
    o.w = (aw0 + aw1 + aw2 + aw3) * inv;
    *(float4*)(agg + (size_t)node * D + q * 4) = o;
}

// ---------------------------------------------------------------------------
// 5) fused SAGE linear, persistent form.
//    Grid = 256 blocks x 512 threads (1 block/CU by LDS, 2 waves/SIMD).
//    Weights staged to LDS ONCE per block; grid-stride over 64-row tiles.
//    Thread (tx=tid&15, ty=tid>>4): rows {ty, ty+32}, cols {tx+16m, m=0..5}.
//    Per k4-step/wave: 192 VALU cyc vs 192 LDS cyc -> VALU-bound with 2 waves/SIMD.
__global__ __launch_bounds__(512, 2) void sage_gemm_kernel(const float* __restrict__ agg,
                                                           const float* __restrict__ hin,
                                                           const float* __restrict__ Wl,
                                                           const float* __restrict__ bl,
                                                           const float* __restrict__ Wr,
                                                           float* __restrict__ out,
                                                           int n, int relu) {
    __shared__ float swl[96 * PAD];  // 38.4 KB
    __shared__ float swr[96 * PAD];  // 38.4 KB
    __shared__ float sa[64 * PAD];   // 25.6 KB
    __shared__ float sx[64 * PAD];   // 25.6 KB  -> 128 KB total

    int tid = threadIdx.x;
    int tx = tid & 15;
    int ty = tid >> 4;  // 0..31

    // stage both weight matrices once (2304 float4 each)
    for (int i = tid; i < 96 * 24; i += 512) {
        int o = i / 24, k4 = i % 24;
        *(float4*)&swl[o * PAD + k4 * 4] = ((const float4*)Wl)[i];
        *(float4*)&swr[o * PAD + k4 * 4] = ((const float4*)Wr)[i];
    }

    int ntiles = (n + 63) >> 6;
    for (int t = blockIdx.x; t < ntiles; t += gridDim.x) {
        int row0 = t << 6;
        int nrows = min(64, n - row0);
        __syncthreads();  // weights ready (first iter) / prev tile done reading
        for (int i = tid; i < nrows * 24; i += 512) {
            int r = i / 24, k4 = i % 24;
            *(float4*)&sa[r * PAD + k4 * 4] = ((const float4*)(agg + (size_t)(row0 + r) * D))[k4];
            *(float4*)&sx[r * PAD + k4 * 4] = ((const float4*)(hin + (size_t)(row0 + r) * D))[k4];
        }
        __syncthreads();

        float acc0[6], acc1[6];
        #pragma unroll
        for (int m = 0; m < 6; ++m) { acc0[m] = 0.f; acc1[m] = 0.f; }

        #pragma unroll 2
        for (int k4 = 0; k4 < 24; ++k4) {
            float4 a0 = *(const float4*)&sa[ty * PAD + k4 * 4];
            float4 a1 = *(const float4*)&sa[(ty + 32) * PAD + k4 * 4];
            float4 x0 = *(const float4*)&sx[ty * PAD + k4 * 4];
            float4 x1 = *(const float4*)&sx[(ty + 32) * PAD + k4 * 4];
            #pragma unroll
            for (int m = 0; m < 6; ++m) {
                int o = tx + 16 * m;
                float4 l = *(const float4*)&swl[o * PAD + k4 * 4];
                float4 r = *(const float4*)&swr[o * PAD + k4 * 4];
                acc0[m] += a0.x * l.x + a0.y * l.y + a0.z * l.z + a0.w * l.w
                         + x0.x * r.x + x0.y * r.y + x0.z * r.z + x0.w * r.w;
                acc1[m] += a1.x * l.x + a1.y * l.y + a1.z * l.z + a1.w * l.w
                         + x1.x * r.x + x1.y * r.y + x1.z * r.z + x1.w * r.w;
            }
        }

        #pragma unroll
        for (int m = 0; m < 6; ++m) {
            int o = tx + 16 * m;
            float b = bl[o];
            float v0 = acc0[m] + b;
            float v1 = acc1[m] + b;
            if (relu) { v0 = fmaxf(v0, 0.f); v1 = fmaxf(v1, 0.f); }
            if (ty < nrows)      out[(size_t)(row0 + ty) * D + o] = v0;
            if (ty + 32 < nrows) out[(size_t)(row0 + ty + 32) * D + o] = v1;
        }
    }
}

// ---------------------------------------------------------------------------
extern "C" void kernel_launch(void* const* d_in, const int* in_sizes, int n_in,
                              void* d_out, int out_size, void* d_ws, size_t ws_size,
                              hipStream_t stream) {
    const float* x   = (const float*)d_in[0];
    const int*   ei  = (const int*)d_in[1];
    const float* Wl1 = (const float*)d_in[2];
    const float* bl1 = (const float*)d_in[3];
    const float* Wr1 = (const float*)d_in[4];
    const float* Wl2 = (const float*)d_in[5];
    const float* bl2 = (const float*)d_in[6];
    const float* Wr2 = (const float*)d_in[7];
    float* out = (float*)d_out;

    int N = in_sizes[0] / D;      // 50000
    int E = in_sizes[1] / 2;      // 800000
    const int* src = ei;
    const int* dst = ei + E;

    // workspace layout
    char* ws = (char*)d_ws;
    float* agg = (float*)ws;                         // N*D floats
    float* h1  = agg + (size_t)N * D;                // N*D floats
    int*   rs  = (int*)(h1 + (size_t)N * D);         // N+1
    int*   cnt = rs + (N + 1);                       // N
    int*   cur = cnt + N;                            // N
    int*   col = cur + N;                            // E

    hipMemsetAsync(cnt, 0, (size_t)2 * N * sizeof(int), stream);

    int eb = (E + 255) / 256;
    hist_kernel<<<eb, 256, 0, stream>>>(dst, cnt, E);
    scan_kernel<<<1, 1024, 0, stream>>>(cnt, rs, N);
    fill_kernel<<<eb, 256, 0, stream>>>(src, dst, rs, cur, col, E);

    int ab = (N * DQ + 255) / 256;

    // layer 1
    aggregate_kernel<<<ab, 256, 0, stream>>>(x, rs, col, agg, N);
    sage_gemm_kernel<<<256, 512, 0, stream>>>(agg, x, Wl1, bl1, Wr1, h1, N, 1);

    // layer 2
    aggregate_kernel<<<ab, 256, 0, stream>>>(h1, rs, col, agg, N);
    sage_gemm_kernel<<<256, 512, 0, stream>>>(agg, h1, Wl2, bl2, Wr2, out, N, 0);
}

// Round 12
// 374.075 us; speedup vs baseline: 1.4934x; 1.1862x over previous
//
#include <hip/hip_runtime.h>
#include <hip/hip_bf16.h>

#define D 96
#define DQ 24    // D/4 float4 groups per row
#define PAD 100  // padded LDS row stride (floats): weight reads 2-way (free), A reads conflict-free

// ---------------------------------------------------------------------------
// 1) histogram of dst -> cnt[n]
__global__ __launch_bounds__(256) void hist_kernel(const int* __restrict__ dst,
                                                   int* __restrict__ cnt, int E) {
    int e = blockIdx.x * 256 + threadIdx.x;
    if (e < E) atomicAdd(&cnt[dst[e]], 1);
}

// ---------------------------------------------------------------------------
// 2a) per-block exclusive scan (coalesced) + block sums. 49 blocks x 1024.
__global__ __launch_bounds__(1024) void scan1_kernel(const int* __restrict__ cnt,
                                                     int* __restrict__ rs,
                                                     int* __restrict__ bsum, int n) {
    __shared__ int buf[1024];
    int t = threadIdx.x;
    int gid = blockIdx.x * 1024 + t;
    int v = (gid < n) ? cnt[gid] : 0;
    buf[t] = v;
    __syncthreads();
    for (int off = 1; off < 1024; off <<= 1) {
        int u = (t >= off) ? buf[t - off] : 0;
        __syncthreads();
        buf[t] += u;
        __syncthreads();
    }
    if (gid < n) rs[gid] = buf[t] - v;          // block-local exclusive
    if (t == 1023) bsum[blockIdx.x] = buf[1023]; // block total
}

// 2b) scan block sums (nb <= 64, one wave) + write rs[n] = grand total
__global__ __launch_bounds__(64) void scan2_kernel(const int* __restrict__ bsum,
                                                   int* __restrict__ boff, int nb,
                                                   int* __restrict__ rs, int n) {
    __shared__ int buf[64];
    int t = threadIdx.x;
    int v = (t < nb) ? bsum[t] : 0;
    buf[t] = v;
    __syncthreads();
    for (int off = 1; off < 64; off <<= 1) {
        int u = (t >= off) ? buf[t - off] : 0;
        __syncthreads();
        buf[t] += u;
        __syncthreads();
    }
    if (t < nb) boff[t] = buf[t] - v;           // exclusive block offsets
    if (t == 63) rs[n] = buf[63];               // == E
}

// 2c) add block offsets (coalesced)
__global__ __launch_bounds__(1024) void scan3_kernel(int* __restrict__ rs,
                                                     const int* __restrict__ boff, int n) {
    int gid = blockIdx.x * 1024 + threadIdx.x;
    if (gid < n) rs[gid] += boff[blockIdx.x];
}

// ---------------------------------------------------------------------------
// 3) fill CSR column (source node) list
__global__ __launch_bounds__(256) void fill_kernel(const int* __restrict__ src,
                                                   const int* __restrict__ dst,
                                                   const int* __restrict__ rs,
                                                   int* __restrict__ cur,
                                                   int* __restrict__ col, int E) {
    int e = blockIdx.x * 256 + threadIdx.x;
    if (e < E) {
        int d = dst[e];
        int pos = rs[d] + atomicAdd(&cur[d], 1);
        col[pos] = src[e];
    }
}

// ---------------------------------------------------------------------------
// 4) mean aggregation: thread = (node, float4-group). 4 independent gather
//    chains in flight (latency-bound on col->gather dependent chain).
__global__ __launch_bounds__(256) void aggregate_kernel(const float* __restrict__ h,
                                                        const int* __restrict__ rs,
                                                        const int* __restrict__ col,
                                                        float* __restrict__ agg, int n) {
    int idx = blockIdx.x * 256 + threadIdx.x;
    if (idx >= n * DQ) return;
    int node = idx / DQ;
    int q = idx - node * DQ;
    int beg = rs[node], end = rs[node + 1];
    float ax0=0.f, ay0=0.f, az0=0.f, aw0=0.f;
    float ax1=0.f, ay1=0.f, az1=0.f, aw1=0.f;
    float ax2=0.f, ay2=0.f, az2=0.f, aw2=0.f;
    float ax3=0.f, ay3=0.f, az3=0.f, aw3=0.f;
    int i = beg;
    for (; i + 4 <= end; i += 4) {
        int s0 = col[i], s1 = col[i+1], s2 = col[i+2], s3 = col[i+3];
        const float4 v0 = *(const float4*)(h + (size_t)s0 * D + q * 4);
        const float4 v1 = *(const float4*)(h + (size_t)s1 * D + q * 4);
        const float4 v2 = *(const float4*)(h + (size_t)s2 * D + q * 4);
        const float4 v3 = *(const float4*)(h + (size_t)s3 * D + q * 4);
        ax0 += v0.x; ay0 += v0.y; az0 += v0.z; aw0 += v0.w;
        ax1 += v1.x; ay1 += v1.y; az1 += v1.z; aw1 += v1.w;
        ax2 += v2.x; ay2 += v2.y; az2 += v2.z; aw2 += v2.w;
        ax3 += v3.x; ay3 += v3.y; az3 += v3.z; aw3 += v3.w;
    }
    for (; i < end; ++i) {
        int s0 = col[i];
        const float4 v0 = *(const float4*)(h + (size_t)s0 * D + q * 4);
        ax0 += v0.x; ay0 += v0.y; az0 += v0.z; aw0 += v0.w;
    }
    float inv = 1.0f / fmaxf((float)(end - beg), 1.0f);
    float4 o;
    o.x = (ax0 + ax1 + ax2 + ax3) * inv;
    o.y = (ay0 + ay1 + ay2 + ay3) * inv;
    o.z = (az0 + az1 + az2 + az3) * inv;
    o.w = (aw0 + aw1 + aw2 + aw3) * inv;
    *(float4*)(agg + (size_t)node * D + q * 4) = o;
}

// ---------------------------------------------------------------------------
// 5) fused SAGE linear, persistent form.
//    Grid = 256 blocks x 512 threads (1 block/CU by LDS, 2 waves/SIMD).
//    Weights staged to LDS ONCE per block; grid-stride over 64-row tiles.
__global__ __launch_bounds__(512, 2) void sage_gemm_kernel(const float* __restrict__ agg,
                                                           const float* __restrict__ hin,
                                                           const float* __restrict__ Wl,
                                                           const float* __restrict__ bl,
                                                           const float* __restrict__ Wr,
                                                           float* __restrict__ out,
                                                           int n, int relu) {
    __shared__ float swl[96 * PAD];  // 38.4 KB
    __shared__ float swr[96 * PAD];  // 38.4 KB
    __shared__ float sa[64 * PAD];   // 25.6 KB
    __shared__ float sx[64 * PAD];   // 25.6 KB  -> 128 KB total

    int tid = threadIdx.x;
    int tx = tid & 15;
    int ty = tid >> 4;  // 0..31

    // stage both weight matrices once (2304 float4 each)
    for (int i = tid; i < 96 * 24; i += 512) {
        int o = i / 24, k4 = i % 24;
        *(float4*)&swl[o * PAD + k4 * 4] = ((const float4*)Wl)[i];
        *(float4*)&swr[o * PAD + k4 * 4] = ((const float4*)Wr)[i];
    }

    int ntiles = (n + 63) >> 6;
    for (int t = blockIdx.x; t < ntiles; t += gridDim.x) {
        int row0 = t << 6;
        int nrows = min(64, n - row0);
        __syncthreads();  // weights ready (first iter) / prev tile done reading
        for (int i = tid; i < nrows * 24; i += 512) {
            int r = i / 24, k4 = i % 24;
            *(float4*)&sa[r * PAD + k4 * 4] = ((const float4*)(agg + (size_t)(row0 + r) * D))[k4];
            *(float4*)&sx[r * PAD + k4 * 4] = ((const float4*)(hin + (size_t)(row0 + r) * D))[k4];
        }
        __syncthreads();

        float acc0[6], acc1[6];
        #pragma unroll
        for (int m = 0; m < 6; ++m) { acc0[m] = 0.f; acc1[m] = 0.f; }

        #pragma unroll 2
        for (int k4 = 0; k4 < 24; ++k4) {
            float4 a0 = *(const float4*)&sa[ty * PAD + k4 * 4];
            float4 a1 = *(const float4*)&sa[(ty + 32) * PAD + k4 * 4];
            float4 x0 = *(const float4*)&sx[ty * PAD + k4 * 4];
            float4 x1 = *(const float4*)&sx[(ty + 32) * PAD + k4 * 4];
            #pragma unroll
            for (int m = 0; m < 6; ++m) {
                int o = tx + 16 * m;
                float4 l = *(const float4*)&swl[o * PAD + k4 * 4];
                float4 r = *(const float4*)&swr[o * PAD + k4 * 4];
                acc0[m] += a0.x * l.x + a0.y * l.y + a0.z * l.z + a0.w * l.w
                         + x0.x * r.x + x0.y * r.y + x0.z * r.z + x0.w * r.w;
                acc1[m] += a1.x * l.x + a1.y * l.y + a1.z * l.z + a1.w * l.w
                         + x1.x * r.x + x1.y * r.y + x1.z * r.z + x1.w * r.w;
            }
        }

        #pragma unroll
        for (int m = 0; m < 6; ++m) {
            int o = tx + 16 * m;
            float b = bl[o];
            float v0 = acc0[m] + b;
            float v1 = acc1[m] + b;
            if (relu) { v0 = fmaxf(v0, 0.f); v1 = fmaxf(v1, 0.f); }
            if (ty < nrows)      out[(size_t)(row0 + ty) * D + o] = v0;
            if (ty + 32 < nrows) out[(size_t)(row0 + ty + 32) * D + o] = v1;
        }
    }
}

// ---------------------------------------------------------------------------
extern "C" void kernel_launch(void* const* d_in, const int* in_sizes, int n_in,
                              void* d_out, int out_size, void* d_ws, size_t ws_size,
                              hipStream_t stream) {
    const float* x   = (const float*)d_in[0];
    const int*   ei  = (const int*)d_in[1];
    const float* Wl1 = (const float*)d_in[2];
    const float* bl1 = (const float*)d_in[3];
    const float* Wr1 = (const float*)d_in[4];
    const float* Wl2 = (const float*)d_in[5];
    const float* bl2 = (const float*)d_in[6];
    const float* Wr2 = (const float*)d_in[7];
    float* out = (float*)d_out;

    int N = in_sizes[0] / D;      // 50000
    int E = in_sizes[1] / 2;      // 800000
    const int* src = ei;
    const int* dst = ei + E;

    // workspace layout
    char* ws = (char*)d_ws;
    float* agg = (float*)ws;                         // N*D floats
    float* h1  = agg + (size_t)N * D;                // N*D floats
    int*   rs  = (int*)(h1 + (size_t)N * D);         // N+1
    int*   cnt = rs + (N + 1);                       // N
    int*   cur = cnt + N;                            // N
    int*   col = cur + N;                            // E
    int*   bsum = col + E;                           // 64
    int*   boff = bsum + 64;                         // 64

    hipMemsetAsync(cnt, 0, (size_t)2 * N * sizeof(int), stream);

    int eb = (E + 255) / 256;
    int nbk = (N + 1023) / 1024;   // 49
    hist_kernel<<<eb, 256, 0, stream>>>(dst, cnt, E);
    scan1_kernel<<<nbk, 1024, 0, stream>>>(cnt, rs, bsum, N);
    scan2_kernel<<<1, 64, 0, stream>>>(bsum, boff, nbk, rs, N);
    scan3_kernel<<<nbk, 1024, 0, stream>>>(rs, boff, N);
    fill_kernel<<<eb, 256, 0, stream>>>(src, dst, rs, cur, col, E);

    int ab = (N * DQ + 255) / 256;

    // layer 1
    aggregate_kernel<<<ab, 256, 0, stream>>>(x, rs, col, agg, N);
    sage_gemm_kernel<<<256, 512, 0, stream>>>(agg, x, Wl1, bl1, Wr1, h1, N, 1);

    // layer 2
    aggregate_kernel<<<ab, 256, 0, stream>>>(h1, rs, col, agg, N);
    sage_gemm_kernel<<<256, 512, 0, stream>>>(agg, h1, Wl2, bl2, Wr2, out, N, 0);
}

// Round 13
// 288.064 us; speedup vs baseline: 1.9393x; 1.2986x over previous
//
#include <hip/hip_runtime.h>
#include <hip/hip_bf16.h>

#define D 96
#define DQ 24     // D/4 float4 groups per row
#define KS_PAD 104  // f16 k-stride pad: 208B rows -> <=2-way banks on B-frag reads

typedef _Float16 half8 __attribute__((ext_vector_type(8)));
typedef float floatx4 __attribute__((ext_vector_type(4)));

// ---------------------------------------------------------------------------
// 1) histogram of dst -> cnt[n]
__global__ __launch_bounds__(256) void hist_kernel(const int* __restrict__ dst,
                                                   int* __restrict__ cnt, int E) {
    int e = blockIdx.x * 256 + threadIdx.x;
    if (e < E) atomicAdd(&cnt[dst[e]], 1);
}

// ---------------------------------------------------------------------------
// 2a) per-block exclusive scan (coalesced) + block sums. 49 blocks x 1024.
__global__ __launch_bounds__(1024) void scan1_kernel(const int* __restrict__ cnt,
                                                     int* __restrict__ rs,
                                                     int* __restrict__ bsum, int n) {
    __shared__ int buf[1024];
    int t = threadIdx.x;
    int gid = blockIdx.x * 1024 + t;
    int v = (gid < n) ? cnt[gid] : 0;
    buf[t] = v;
    __syncthreads();
    for (int off = 1; off < 1024; off <<= 1) {
        int u = (t >= off) ? buf[t - off] : 0;
        __syncthreads();
        buf[t] += u;
        __syncthreads();
    }
    if (gid < n) rs[gid] = buf[t] - v;          // block-local exclusive
    if (t == 1023) bsum[blockIdx.x] = buf[1023]; // block total
}

// 2b) scan block sums (nb <= 64, one wave) + write rs[n] = grand total
__global__ __launch_bounds__(64) void scan2_kernel(const int* __restrict__ bsum,
                                                   int* __restrict__ boff, int nb,
                                                   int* __restrict__ rs, int n) {
    __shared__ int buf[64];
    int t = threadIdx.x;
    int v = (t < nb) ? bsum[t] : 0;
    buf[t] = v;
    __syncthreads();
    for (int off = 1; off < 64; off <<= 1) {
        int u = (t >= off) ? buf[t - off] : 0;
        __syncthreads();
        buf[t] += u;
        __syncthreads();
    }
    if (t < nb) boff[t] = buf[t] - v;           // exclusive block offsets
    if (t == 63) rs[n] = buf[63];               // == E
}

// 2c) add block offsets (coalesced)
__global__ __launch_bounds__(1024) void scan3_kernel(int* __restrict__ rs,
                                                     const int* __restrict__ boff, int n) {
    int gid = blockIdx.x * 1024 + threadIdx.x;
    if (gid < n) rs[gid] += boff[blockIdx.x];
}

// ---------------------------------------------------------------------------
// 3) fill CSR column (source node) list
__global__ __launch_bounds__(256) void fill_kernel(const int* __restrict__ src,
                                                   const int* __restrict__ dst,
                                                   const int* __restrict__ rs,
                                                   int* __restrict__ cur,
                                                   int* __restrict__ col, int E) {
    int e = blockIdx.x * 256 + threadIdx.x;
    if (e < E) {
        int d = dst[e];
        int pos = rs[d] + atomicAdd(&cur[d], 1);
        col[pos] = src[e];
    }
}

// ---------------------------------------------------------------------------
// 4) mean aggregation: thread = (node, float4-group). 4 independent gather
//    chains in flight (latency-bound on col->gather dependent chain).
__global__ __launch_bounds__(256) void aggregate_kernel(const float* __restrict__ h,
                                                        const int* __restrict__ rs,
                                                        const int* __restrict__ col,
                                                        float* __restrict__ agg, int n) {
    int idx = blockIdx.x * 256 + threadIdx.x;
    if (idx >= n * DQ) return;
    int node = idx / DQ;
    int q = idx - node * DQ;
    int beg = rs[node], end = rs[node + 1];
    float ax0=0.f, ay0=0.f, az0=0.f, aw0=0.f;
    float ax1=0.f, ay1=0.f, az1=0.f, aw1=0.f;
    float ax2=0.f, ay2=0.f, az2=0.f, aw2=0.f;
    float ax3=0.f, ay3=0.f, az3=0.f, aw3=0.f;
    int i = beg;
    for (; i + 4 <= end; i += 4) {
        int s0 = col[i], s1 = col[i+1], s2 = col[i+2], s3 = col[i+3];
        const float4 v0 = *(const float4*)(h + (size_t)s0 * D + q * 4);
        const float4 v1 = *(const float4*)(h + (size_t)s1 * D + q * 4);
        const float4 v2 = *(const float4*)(h + (size_t)s2 * D + q * 4);
        const float4 v3 = *(const float4*)(h + (size_t)s3 * D + q * 4);
        ax0 += v0.x; ay0 += v0.y; az0 += v0.z; aw0 += v0.w;
        ax1 += v1.x; ay1 += v1.y; az1 += v1.z; aw1 += v1.w;
        ax2 += v2.x; ay2 += v2.y; az2 += v2.z; aw2 += v2.w;
        ax3 += v3.x; ay3 += v3.y; az3 += v3.z; aw3 += v3.w;
    }
    for (; i < end; ++i) {
        int s0 = col[i];
        const float4 v0 = *(const float4*)(h + (size_t)s0 * D + q * 4);
        ax0 += v0.x; ay0 += v0.y; az0 += v0.z; aw0 += v0.w;
    }
    float inv = 1.0f / fmaxf((float)(end - beg), 1.0f);
    float4 o;
    o.x = (ax0 + ax1 + ax2 + ax3) * inv;
    o.y = (ay0 + ay1 + ay2 + ay3) * inv;
    o.z = (az0 + az1 + az2 + az3) * inv;
    o.w = (aw0 + aw1 + aw2 + aw3) * inv;
    *(float4*)(agg + (size_t)node * D + q * 4) = o;
}

// ---------------------------------------------------------------------------
// 5) fused SAGE linear via MFMA f16 (fp32 accumulate).
//    out[r][o] = sum_k agg[r][k]*Wl[o][k] + x[r][k]*Wr[o][k] + bl[o] (+relu)
//    Block 256 thr = 4 waves; 64 rows/block; wave w owns rows w*16..w*16+15.
//    W staged f16 in LDS (~40KB -> multiple blocks/CU); A-rows converted to
//    f16 fragments in regs. 16x16x32 MFMA, K=96 -> 3 ksteps x 2 matmuls.
//    Fragment mapping (guide §3, m89-verified C/D): A/B lane m+16g holds 8
//    contiguous k at 8g; D: col=lane&15, row=(lane>>4)*4+reg.
__global__ __launch_bounds__(256) void sage_gemm_mfma(const float* __restrict__ agg,
                                                      const float* __restrict__ hin,
                                                      const float* __restrict__ Wl,
                                                      const float* __restrict__ bl,
                                                      const float* __restrict__ Wr,
                                                      float* __restrict__ out,
                                                      int n, int relu) {
    __shared__ _Float16 swl[96 * KS_PAD];  // 20.0 KB
    __shared__ _Float16 swr[96 * KS_PAD];  // 20.0 KB

    int tid = threadIdx.x;
    // stage + convert both weight matrices to f16 LDS
    for (int i = tid; i < 96 * 96; i += 256) {
        int o = i / 96, k = i - o * 96;
        swl[o * KS_PAD + k] = (_Float16)Wl[i];
        swr[o * KS_PAD + k] = (_Float16)Wr[i];
    }
    __syncthreads();

    int lane = tid & 63;
    int w = tid >> 6;          // wave 0..3
    int m = lane & 15;         // A row-within-tile / B col / D col
    int g = lane >> 4;         // k-group 0..3

    int arow = blockIdx.x * 64 + w * 16 + m;
    int rload = (arow < n) ? arow : (n - 1);   // clamp; OOB D-rows never stored

    // A fragments: 3 ksteps x {agg, x}; lane holds k = ks*32 + g*8 .. +7
    half8 af[3], xf[3];
    #pragma unroll
    for (int ks = 0; ks < 3; ++ks) {
        const float* pa = agg + (size_t)rload * D + ks * 32 + g * 8;
        const float* px = hin + (size_t)rload * D + ks * 32 + g * 8;
        float4 a0 = *(const float4*)pa;
        float4 a1 = *(const float4*)(pa + 4);
        float4 x0 = *(const float4*)px;
        float4 x1 = *(const float4*)(px + 4);
        af[ks] = (half8){(_Float16)a0.x, (_Float16)a0.y, (_Float16)a0.z, (_Float16)a0.w,
                         (_Float16)a1.x, (_Float16)a1.y, (_Float16)a1.z, (_Float16)a1.w};
        xf[ks] = (half8){(_Float16)x0.x, (_Float16)x0.y, (_Float16)x0.z, (_Float16)x0.w,
                         (_Float16)x1.x, (_Float16)x1.y, (_Float16)x1.z, (_Float16)x1.w};
    }

    int row0 = blockIdx.x * 64 + w * 16 + g * 4;  // D rows for this lane
    #pragma unroll
    for (int ct = 0; ct < 6; ++ct) {
        int o = ct * 16 + m;    // this lane's output column (= B's n)
        floatx4 acc = {0.f, 0.f, 0.f, 0.f};
        #pragma unroll
        for (int ks = 0; ks < 3; ++ks) {
            half8 bwl = *(const half8*)&swl[o * KS_PAD + ks * 32 + g * 8];
            acc = __builtin_amdgcn_mfma_f32_16x16x32_f16(af[ks], bwl, acc, 0, 0, 0);
            half8 bwr = *(const half8*)&swr[o * KS_PAD + ks * 32 + g * 8];
            acc = __builtin_amdgcn_mfma_f32_16x16x32_f16(xf[ks], bwr, acc, 0, 0, 0);
        }
        float b = bl[o];
        #pragma unroll
        for (int p = 0; p < 4; ++p) {
            int orow = row0 + p;
            float v = acc[p] + b;
            if (relu) v = fmaxf(v, 0.f);
            if (orow < n) out[(size_t)orow * D + o] = v;
        }
    }
}

// ---------------------------------------------------------------------------
extern "C" void kernel_launch(void* const* d_in, const int* in_sizes, int n_in,
                              void* d_out, int out_size, void* d_ws, size_t ws_size,
                              hipStream_t stream) {
    const float* x   = (const float*)d_in[0];
    const int*   ei  = (const int*)d_in[1];
    const float* Wl1 = (const float*)d_in[2];
    const float* bl1 = (const float*)d_in[3];
    const float* Wr1 = (const float*)d_in[4];
    const float* Wl2 = (const float*)d_in[5];
    const float* bl2 = (const float*)d_in[6];
    const float* Wr2 = (const float*)d_in[7];
    float* out = (float*)d_out;

    int N = in_sizes[0] / D;      // 50000
    int E = in_sizes[1] / 2;      // 800000
    const int* src = ei;
    const int* dst = ei + E;

    // workspace layout
    char* ws = (char*)d_ws;
    float* agg = (float*)ws;                         // N*D floats
    float* h1  = agg + (size_t)N * D;                // N*D floats
    int*   rs  = (int*)(h1 + (size_t)N * D);         // N+1
    int*   cnt = rs + (N + 1);                       // N
    int*   cur = cnt + N;                            // N
    int*   col = cur + N;                            // E
    int*   bsum = col + E;                           // 64
    int*   boff = bsum + 64;                         // 64

    hipMemsetAsync(cnt, 0, (size_t)2 * N * sizeof(int), stream);

    int eb = (E + 255) / 256;
    int nbk = (N + 1023) / 1024;   // 49
    hist_kernel<<<eb, 256, 0, stream>>>(dst, cnt, E);
    scan1_kernel<<<nbk, 1024, 0, stream>>>(cnt, rs, bsum, N);
    scan2_kernel<<<1, 64, 0, stream>>>(bsum, boff, nbk, rs, N);
    scan3_kernel<<<nbk, 1024, 0, stream>>>(rs, boff, N);
    fill_kernel<<<eb, 256, 0, stream>>>(src, dst, rs, cur, col, E);

    int ab = (N * DQ + 255) / 256;
    int gb = (N + 63) / 64;        // 782

    // layer 1
    aggregate_kernel<<<ab, 256, 0, stream>>>(x, rs, col, agg, N);
    sage_gemm_mfma<<<gb, 256, 0, stream>>>(agg, x, Wl1, bl1, Wr1, h1, N, 1);

    // layer 2
    aggregate_kernel<<<ab, 256, 0, stream>>>(h1, rs, col, agg, N);
    sage_gemm_mfma<<<gb, 256, 0, stream>>>(agg, h1, Wl2, bl2, Wr2, out, N, 0);
}

// Round 14
// 258.128 us; speedup vs baseline: 2.1642x; 1.1160x over previous
//
#include <hip/hip_runtime.h>
#include <hip/hip_bf16.h>

#define D 96
#define DQH 12      // 96/8 half8 groups per row
#define KS_PAD 104  // f16 k-stride pad for LDS weights

typedef _Float16 half8 __attribute__((ext_vector_type(8)));
typedef _Float16 half4 __attribute__((ext_vector_type(4)));
typedef float floatx4 __attribute__((ext_vector_type(4)));

// ---------------------------------------------------------------------------
// 0) fp32 -> fp16 conversion (4 elems/thread)
__global__ __launch_bounds__(256) void cvt_kernel(const float* __restrict__ in,
                                                  _Float16* __restrict__ out, int n4) {
    int i = blockIdx.x * 256 + threadIdx.x;
    if (i < n4) {
        float4 v = ((const float4*)in)[i];
        half4 o = { (_Float16)v.x, (_Float16)v.y, (_Float16)v.z, (_Float16)v.w };
        ((half4*)out)[i] = o;
    }
}

// ---------------------------------------------------------------------------
// 1) histogram of dst -> cnt[n]
__global__ __launch_bounds__(256) void hist_kernel(const int* __restrict__ dst,
                                                   int* __restrict__ cnt, int E) {
    int e = blockIdx.x * 256 + threadIdx.x;
    if (e < E) atomicAdd(&cnt[dst[e]], 1);
}

// ---------------------------------------------------------------------------
// 2a) per-block exclusive scan + block sums. 49 blocks x 1024.
__global__ __launch_bounds__(1024) void scan1_kernel(const int* __restrict__ cnt,
                                                     int* __restrict__ rs,
                                                     int* __restrict__ bsum, int n) {
    __shared__ int buf[1024];
    int t = threadIdx.x;
    int gid = blockIdx.x * 1024 + t;
    int v = (gid < n) ? cnt[gid] : 0;
    buf[t] = v;
    __syncthreads();
    for (int off = 1; off < 1024; off <<= 1) {
        int u = (t >= off) ? buf[t - off] : 0;
        __syncthreads();
        buf[t] += u;
        __syncthreads();
    }
    if (gid < n) rs[gid] = buf[t] - v;
    if (t == 1023) bsum[blockIdx.x] = buf[1023];
}

// 2b) scan block sums (one wave) + write rs[n] = E
__global__ __launch_bounds__(64) void scan2_kernel(const int* __restrict__ bsum,
                                                   int* __restrict__ boff, int nb,
                                                   int* __restrict__ rs, int n) {
    __shared__ int buf[64];
    int t = threadIdx.x;
    int v = (t < nb) ? bsum[t] : 0;
    buf[t] = v;
    __syncthreads();
    for (int off = 1; off < 64; off <<= 1) {
        int u = (t >= off) ? buf[t - off] : 0;
        __syncthreads();
        buf[t] += u;
        __syncthreads();
    }
    if (t < nb) boff[t] = buf[t] - v;
    if (t == 63) rs[n] = buf[63];
}

// 2c) add block offsets; also materialize cur = rs (fill's atomic cursor)
__global__ __launch_bounds__(1024) void scan3_kernel(int* __restrict__ rs,
                                                     int* __restrict__ cur,
                                                     const int* __restrict__ boff, int n) {
    int gid = blockIdx.x * 1024 + threadIdx.x;
    if (gid < n) {
        int v = rs[gid] + boff[blockIdx.x];
        rs[gid] = v;
        cur[gid] = v;
    }
}

// ---------------------------------------------------------------------------
// 3) fill CSR columns: pos = atomicAdd(cur[d]) directly (no rs read)
__global__ __launch_bounds__(256) void fill_kernel(const int* __restrict__ src,
                                                   const int* __restrict__ dst,
                                                   int* __restrict__ cur,
                                                   int* __restrict__ col, int E) {
    int e = blockIdx.x * 256 + threadIdx.x;
    if (e < E) {
        int pos = atomicAdd(&cur[dst[e]], 1);
        col[pos] = src[e];
    }
}

// ---------------------------------------------------------------------------
// 4) mean aggregation fp16 in/out, fp32 accumulate.
//    thread = (node, half8-group); 4 independent gather chains.
__global__ __launch_bounds__(256) void aggregate_f16(const _Float16* __restrict__ h,
                                                     const int* __restrict__ rs,
                                                     const int* __restrict__ col,
                                                     _Float16* __restrict__ agg, int n) {
    int idx = blockIdx.x * 256 + threadIdx.x;
    if (idx >= n * DQH) return;
    int node = idx / DQH;
    int q = idx - node * DQH;
    int beg = rs[node], end = rs[node + 1];
    float a0[8] = {0,0,0,0,0,0,0,0}, a1[8] = {0,0,0,0,0,0,0,0};
    float a2[8] = {0,0,0,0,0,0,0,0}, a3[8] = {0,0,0,0,0,0,0,0};
    int i = beg;
    for (; i + 4 <= end; i += 4) {
        int s0 = col[i], s1 = col[i+1], s2 = col[i+2], s3 = col[i+3];
        half8 v0 = *(const half8*)(h + (size_t)s0 * D + q * 8);
        half8 v1 = *(const half8*)(h + (size_t)s1 * D + q * 8);
        half8 v2 = *(const half8*)(h + (size_t)s2 * D + q * 8);
        half8 v3 = *(const half8*)(h + (size_t)s3 * D + q * 8);
        #pragma unroll
        for (int j = 0; j < 8; ++j) {
            a0[j] += (float)v0[j]; a1[j] += (float)v1[j];
            a2[j] += (float)v2[j]; a3[j] += (float)v3[j];
        }
    }
    for (; i < end; ++i) {
        int s0 = col[i];
        half8 v0 = *(const half8*)(h + (size_t)s0 * D + q * 8);
        #pragma unroll
        for (int j = 0; j < 8; ++j) a0[j] += (float)v0[j];
    }
    float inv = 1.0f / fmaxf((float)(end - beg), 1.0f);
    half8 o;
    #pragma unroll
    for (int j = 0; j < 8; ++j) o[j] = (_Float16)((a0[j] + a1[j] + a2[j] + a3[j]) * inv);
    *(half8*)(agg + (size_t)node * D + q * 8) = o;
}

// ---------------------------------------------------------------------------
// 5) fused SAGE linear via MFMA f16 (fp32 accumulate), fp16 A-inputs.
//    Block 256 = 4 waves; 64 rows/block; 16x16x32, K=96 -> 3 ksteps x 2 mm.
//    out16 (layer 1, relu) or out32 (layer 2 -> d_out).
__global__ __launch_bounds__(256) void sage_gemm_mfma(const _Float16* __restrict__ agg,
                                                      const _Float16* __restrict__ hin,
                                                      const float* __restrict__ Wl,
                                                      const float* __restrict__ bl,
                                                      const float* __restrict__ Wr,
                                                      _Float16* __restrict__ out16,
                                                      float* __restrict__ out32,
                                                      int n, int relu) {
    __shared__ _Float16 swl[96 * KS_PAD];  // 20.0 KB
    __shared__ _Float16 swr[96 * KS_PAD];  // 20.0 KB

    int tid = threadIdx.x;
    for (int i = tid; i < 96 * 96; i += 256) {
        int o = i / 96, k = i - o * 96;
        swl[o * KS_PAD + k] = (_Float16)Wl[i];
        swr[o * KS_PAD + k] = (_Float16)Wr[i];
    }
    __syncthreads();

    int lane = tid & 63;
    int w = tid >> 6;
    int m = lane & 15;
    int g = lane >> 4;

    int arow = blockIdx.x * 64 + w * 16 + m;
    int rload = (arow < n) ? arow : (n - 1);

    half8 af[3], xf[3];
    #pragma unroll
    for (int ks = 0; ks < 3; ++ks) {
        af[ks] = *(const half8*)(agg + (size_t)rload * D + ks * 32 + g * 8);
        xf[ks] = *(const half8*)(hin + (size_t)rload * D + ks * 32 + g * 8);
    }

    int row0 = blockIdx.x * 64 + w * 16 + g * 4;
    #pragma unroll
    for (int ct = 0; ct < 6; ++ct) {
        int o = ct * 16 + m;
        floatx4 acc = {0.f, 0.f, 0.f, 0.f};
        #pragma unroll
        for (int ks = 0; ks < 3; ++ks) {
            acc = __builtin_amdgcn_mfma_f32_16x16x32_f16(af[ks],
                    *(const half8*)&swl[o * KS_PAD + ks * 32 + g * 8], acc, 0, 0, 0);
            acc = __builtin_amdgcn_mfma_f32_16x16x32_f16(xf[ks],
                    *(const half8*)&swr[o * KS_PAD + ks * 32 + g * 8], acc, 0, 0, 0);
        }
        float b = bl[o];
        #pragma unroll
        for (int p = 0; p < 4; ++p) {
            int orow = row0 + p;
            float v = acc[p] + b;
            if (relu) v = fmaxf(v, 0.f);
            if (orow < n) {
                if (out32) out32[(size_t)orow * D + o] = v;
                else       out16[(size_t)orow * D + o] = (_Float16)v;
            }
        }
    }
}

// ---------------------------------------------------------------------------
extern "C" void kernel_launch(void* const* d_in, const int* in_sizes, int n_in,
                              void* d_out, int out_size, void* d_ws, size_t ws_size,
                              hipStream_t stream) {
    const float* x   = (const float*)d_in[0];
    const int*   ei  = (const int*)d_in[1];
    const float* Wl1 = (const float*)d_in[2];
    const float* bl1 = (const float*)d_in[3];
    const float* Wr1 = (const float*)d_in[4];
    const float* Wl2 = (const float*)d_in[5];
    const float* bl2 = (const float*)d_in[6];
    const float* Wr2 = (const float*)d_in[7];
    float* out = (float*)d_out;

    int N = in_sizes[0] / D;      // 50000
    int E = in_sizes[1] / 2;      // 800000
    const int* src = ei;
    const int* dst = ei + E;

    // workspace layout (f16 activations)
    char* ws = (char*)d_ws;
    _Float16* xh   = (_Float16*)ws;                        // N*D f16 (9.6MB)
    _Float16* h1h  = xh + (size_t)N * D;                   // N*D f16
    _Float16* aggh = h1h + (size_t)N * D;                  // N*D f16
    int* rs   = (int*)(aggh + (size_t)N * D);              // N+1
    int* cnt  = rs + (N + 1);                              // N
    int* cur  = cnt + N;                                   // N
    int* col  = cur + N;                                   // E
    int* bsum = col + E;                                   // 64
    int* boff = bsum + 64;                                 // 64

    hipMemsetAsync(cnt, 0, (size_t)N * sizeof(int), stream);

    int eb  = (E + 255) / 256;
    int nbk = (N + 1023) / 1024;   // 49
    int n4  = N * D / 4;           // fp32->fp16 quads

    cvt_kernel<<<(n4 + 255) / 256, 256, 0, stream>>>(x, xh, n4);
    hist_kernel<<<eb, 256, 0, stream>>>(dst, cnt, E);
    scan1_kernel<<<nbk, 1024, 0, stream>>>(cnt, rs, bsum, N);
    scan2_kernel<<<1, 64, 0, stream>>>(bsum, boff, nbk, rs, N);
    scan3_kernel<<<nbk, 1024, 0, stream>>>(rs, cur, boff, N);
    fill_kernel<<<eb, 256, 0, stream>>>(src, dst, cur, col, E);

    int ab = (N * DQH + 255) / 256;
    int gb = (N + 63) / 64;        // 782

    // layer 1 (f16 out + relu)
    aggregate_f16<<<ab, 256, 0, stream>>>(xh, rs, col, aggh, N);
    sage_gemm_mfma<<<gb, 256, 0, stream>>>(aggh, xh, Wl1, bl1, Wr1, h1h, nullptr, N, 1);

    // layer 2 (fp32 out to d_out)
    aggregate_f16<<<ab, 256, 0, stream>>>(h1h, rs, col, aggh, N);
    sage_gemm_mfma<<<gb, 256, 0, stream>>>(aggh, h1h, Wl2, bl2, Wr2, nullptr, out, N, 0);
}